// Round 1
// 383.465 us; speedup vs baseline: 1.0631x; 1.0631x over previous
//
#include <hip/hip_runtime.h>
#include <hip/hip_bf16.h>

#define N 6144
#define EMB 256
#define HID 128
#define E_POS 98304
#define E_NEG 24576
#define E_POT 262144
#define E_TOT (E_POS + E_NEG + E_POT)   // 385024
#define SIGMA_INV (1.0f / 100.0f)
#define T_DEL 0.1f

__device__ __forceinline__ float sigm(float x) { return 1.0f / (1.0f + __expf(-x)); }

// round-to-nearest-even fp32 -> bf16 (values are finite/normal here)
__device__ __forceinline__ unsigned short f2bf(float f) {
    unsigned u = __float_as_uint(f);
    u += 0x7fffu + ((u >> 16) & 1u);
    return (unsigned short)(u >> 16);
}

typedef __attribute__((ext_vector_type(8))) short bf16x8;
typedef __attribute__((ext_vector_type(4))) float f32x4;

// ---------------------------------------------------------------------------
// MLP: latent = relu(emb @ W1 + b1) @ W2 + b2, both branches (blockIdx.y).
// 128 threads / 16 rows; thread = 2 cols x 8 rows; emb staged in LDS.
// Latents stored as bf16 (so both fit one XCD's 4 MiB L2 in edge_kernel).
// Also zeroes the loss accumulators (stream-ordered before edge_kernel).
// ---------------------------------------------------------------------------
#define ROWS 16
#define EPITCH 260
#define HPITCH 132

__global__ __launch_bounds__(128)
void mlp_kernel(const float* __restrict__ emb,
                const float* __restrict__ Wl1, const float* __restrict__ bl1,
                const float* __restrict__ Wl2, const float* __restrict__ bl2,
                const float* __restrict__ Wa1, const float* __restrict__ ba1,
                const float* __restrict__ Wa2, const float* __restrict__ ba2,
                unsigned short* __restrict__ latL, unsigned short* __restrict__ latA,
                float* __restrict__ ws_acc)
{
    const int t = threadIdx.x;
    const int branch = blockIdx.y;
    const float* W1 = branch ? Wa1 : Wl1;
    const float* b1 = branch ? ba1 : bl1;
    const float* W2 = branch ? Wa2 : Wl2;
    const float* b2 = branch ? ba2 : bl2;
    unsigned short* lat = branch ? latA : latL;

    if (blockIdx.x == 0 && branch == 0 && t == 0) { ws_acc[0] = 0.f; ws_acc[1] = 0.f; }

    __shared__ float embS[ROWS * EPITCH];
    __shared__ float hidS[ROWS * HPITCH];

    const int row0 = blockIdx.x * ROWS;

    for (int idx = t; idx < ROWS * (EMB / 4); idx += 128) {
        int r = idx >> 6;
        int c4 = (idx & 63) << 2;
        *(float4*)(embS + r * EPITCH + c4) =
            *(const float4*)(emb + (size_t)(row0 + r) * EMB + c4);
    }
    __syncthreads();

    const int h0 = (t & 63) * 2;
    const int rb = (t >> 6) * 8;

    float accx[8], accy[8];

    // layer 1
    {
        float2 bb = *(const float2*)(b1 + h0);
        #pragma unroll
        for (int i = 0; i < 8; i++) { accx[i] = bb.x; accy[i] = bb.y; }
        for (int k = 0; k < EMB; k += 4) {
            float2 w0 = *(const float2*)(W1 + (size_t)(k + 0) * HID + h0);
            float2 w1 = *(const float2*)(W1 + (size_t)(k + 1) * HID + h0);
            float2 w2 = *(const float2*)(W1 + (size_t)(k + 2) * HID + h0);
            float2 w3 = *(const float2*)(W1 + (size_t)(k + 3) * HID + h0);
            #pragma unroll
            for (int i = 0; i < 8; i++) {
                float4 e = *(const float4*)(embS + (rb + i) * EPITCH + k);
                accx[i] += e.x * w0.x + e.y * w1.x + e.z * w2.x + e.w * w3.x;
                accy[i] += e.x * w0.y + e.y * w1.y + e.z * w2.y + e.w * w3.y;
            }
        }
        #pragma unroll
        for (int i = 0; i < 8; i++) {
            *(float2*)(hidS + (rb + i) * HPITCH + h0) =
                make_float2(fmaxf(accx[i], 0.f), fmaxf(accy[i], 0.f));
        }
    }
    __syncthreads();

    // layer 2
    {
        float2 bb = *(const float2*)(b2 + h0);
        #pragma unroll
        for (int i = 0; i < 8; i++) { accx[i] = bb.x; accy[i] = bb.y; }
        for (int k = 0; k < HID; k += 4) {
            float2 w0 = *(const float2*)(W2 + (size_t)(k + 0) * HID + h0);
            float2 w1 = *(const float2*)(W2 + (size_t)(k + 1) * HID + h0);
            float2 w2 = *(const float2*)(W2 + (size_t)(k + 2) * HID + h0);
            float2 w3 = *(const float2*)(W2 + (size_t)(k + 3) * HID + h0);
            #pragma unroll
            for (int i = 0; i < 8; i++) {
                float4 e = *(const float4*)(hidS + (rb + i) * HPITCH + k);
                accx[i] += e.x * w0.x + e.y * w1.x + e.z * w2.x + e.w * w3.x;
                accy[i] += e.x * w0.y + e.y * w1.y + e.z * w2.y + e.w * w3.y;
            }
        }
        #pragma unroll
        for (int i = 0; i < 8; i++) {
            unsigned short bx = f2bf(accx[i]);
            unsigned short by = f2bf(accy[i]);
            *(ushort2*)(lat + (size_t)(row0 + rb + i) * HID + h0) = make_ushort2(bx, by);
        }
    }
}

// ---------------------------------------------------------------------------
// Edge kernel, MFMA version.
// 1 edge per lane: each lane owns edge e = blockIdx.x*256 + t, loads its own
// (i,j) and issues its own aa/fd gather -> 64 gathers in flight per wave.
// Then 4 sub-batches of 16 edges: one mfma_f32_16x16x32_bf16 chain (K=128)
// per latent matrix computes all 16 dot products; the needed values are the
// diagonal of the 16x16 C tile (col = lane&15, row = (lane>>4)*4 + reg), so
// the reduction is free. A/B fragments use identical per-lane k-addressing,
// making the dot invariant to the exact per-lane k permutation.
// E_POS/E_NEG/E_POT are all multiples of 256 -> edge class uniform per block:
//   blocks [0,384): pos, [384,480): neg, [480,1504): pot. No class divergence.
// ---------------------------------------------------------------------------
__global__ __launch_bounds__(256, 4)
void edge_kernel(const unsigned short* __restrict__ latL,
                 const unsigned short* __restrict__ latA,
                 const float* __restrict__ aa, const float* __restrict__ fd,
                 const int* __restrict__ ei, const int* __restrict__ ne,
                 const int* __restrict__ pe,
                 const float* __restrict__ ewp, const float* __restrict__ swp,
                 float* __restrict__ out, float* __restrict__ ws_acc)
{
    const int t = threadIdx.x;
    const int lane = t & 63;
    const int B = blockIdx.x;
    const int e = B * 256 + t;          // this lane's own edge

    // block-uniform class
    int i, j, cls;
    if (B < 384)      { cls = 0; i = ei[e]; j = ei[E_POS + e]; }
    else if (B < 480) { cls = 1; int u = e - E_POS; i = ne[u]; j = ne[E_NEG + u]; }
    else              { cls = 2; int u = e - (E_POS + E_NEG); i = pe[u]; j = pe[E_POT + u]; }

    // issue this lane's random gathers immediately (64 in flight per wave)
    const size_t o2 = (size_t)i * N + j;
    const float av = aa[o2];
    const float fv = (cls < 2) ? fd[o2] : 0.f;

    const float ew = ewp[0];
    const float sw = swp[0];

    const int s   = lane & 15;          // edge-within-subbatch / C column
    const int kq  = lane >> 4;          // k-quad for A/B fragments
    const int koff = kq * 8;            // 8 bf16 per lane per K=32 chunk
    const int r   = lane & 3;           // C reg index on the diagonal
    const bool active = (kq == (s >> 2));   // this lane holds C[s][s]
    const int ebase = B * 256 + (t & 192);  // wave's first edge

    float posAcc = 0.f, negAcc = 0.f;

    #pragma unroll
    for (int b = 0; b < 4; b++) {
        const int src = (b << 4) + s;   // owner lane of edge s in sub-batch b
        const int ii = __shfl(i, src, 64);
        const int jj = __shfl(j, src, 64);

        const unsigned short* pLi = latL + ((size_t)ii << 7) + koff;
        const unsigned short* pLj = latL + ((size_t)jj << 7) + koff;
        const unsigned short* pAi = latA + ((size_t)ii << 7) + koff;
        const unsigned short* pAj = latA + ((size_t)jj << 7) + koff;

        f32x4 accL = {0.f, 0.f, 0.f, 0.f};
        f32x4 accA = {0.f, 0.f, 0.f, 0.f};
        #pragma unroll
        for (int m = 0; m < 4; m++) {
            bf16x8 aL = *(const bf16x8*)(pLi + m * 32);
            bf16x8 bL = *(const bf16x8*)(pLj + m * 32);
            bf16x8 aA = *(const bf16x8*)(pAi + m * 32);
            bf16x8 bA = *(const bf16x8*)(pAj + m * 32);
            accL = __builtin_amdgcn_mfma_f32_16x16x32_bf16(aL, bL, accL, 0, 0, 0);
            accA = __builtin_amdgcn_mfma_f32_16x16x32_bf16(aA, bA, accA, 0, 0, 0);
        }

        const float avd = __shfl(av, src, 64);
        const float fvd = __shfl(fv, src, 64);

        if (active) {
            // static-indexed diagonal extraction (reg = s&3 = lane&3)
            float dl = (r == 0) ? accL[0] : (r == 1) ? accL[1] : (r == 2) ? accL[2] : accL[3];
            float da = (r == 0) ? accA[0] : (r == 1) ? accA[1] : (r == 2) ? accA[2] : accA[3];
            const float lc = sigm(dl);
            const float ac = sigm(da * avd);
            const float p  = sigm(ew * lc + sw * ac);
            if (cls == 2) {
                const int qq = ebase + (b << 4) + s - (E_POS + E_NEG);
                out[1 + qq] = (p < T_DEL) ? 0.f : p;
            } else if (cls == 0) {
                const float f = fvd * SIGMA_INV;
                const float w = __expf(-f * f);
                const float dd = p - 1.f;
                posAcc += w * dd * dd;
            } else {
                const float f = fvd * SIGMA_INV;
                const float w = __expf(f * f);
                negAcc += w * p * p;
            }
        }
    }

    if (cls < 2) {
        #pragma unroll
        for (int off = 32; off >= 1; off >>= 1) {
            posAcc += __shfl_xor(posAcc, off, 64);
            negAcc += __shfl_xor(negAcc, off, 64);
        }
        __shared__ float red[4][2];
        const int wslot = t >> 6;
        if (lane == 0) { red[wslot][0] = posAcc; red[wslot][1] = negAcc; }
        __syncthreads();
        if (t == 0) {
            float p = 0.f, n2 = 0.f;
            #pragma unroll
            for (int w = 0; w < 4; w++) { p += red[w][0]; n2 += red[w][1]; }
            atomicAdd(&ws_acc[0], p);
            atomicAdd(&ws_acc[1], n2);
        }
    }
}

__global__ void finalize_kernel(const float* __restrict__ ws_acc, float* __restrict__ out)
{
    if (threadIdx.x == 0)
        out[0] = (ws_acc[0] + ws_acc[1]) * ((float)N / (float)(E_POS + E_NEG));
}

extern "C" void kernel_launch(void* const* d_in, const int* in_sizes, int n_in,
                              void* d_out, int out_size, void* d_ws, size_t ws_size,
                              hipStream_t stream)
{
    const float* emb = (const float*)d_in[0];
    const float* aa  = (const float*)d_in[1];
    const float* fd  = (const float*)d_in[2];
    const float* Wl1 = (const float*)d_in[3];
    const float* bl1 = (const float*)d_in[4];
    const float* Wl2 = (const float*)d_in[5];
    const float* bl2 = (const float*)d_in[6];
    const float* Wa1 = (const float*)d_in[7];
    const float* ba1 = (const float*)d_in[8];
    const float* Wa2 = (const float*)d_in[9];
    const float* ba2 = (const float*)d_in[10];
    const float* ewp = (const float*)d_in[11];
    const float* swp = (const float*)d_in[12];
    const int* ei = (const int*)d_in[13];
    const int* ne = (const int*)d_in[14];
    const int* pe = (const int*)d_in[15];

    float* out = (float*)d_out;
    float* ws  = (float*)d_ws;
    // ws layout: [0..1] loss accumulators (zeroed by mlp_kernel), pad to 256B,
    // then latL [N*HID] bf16 and latA [N*HID] bf16 (~3.1 MB total)
    unsigned short* latL = (unsigned short*)(ws + 64);
    unsigned short* latA = latL + (size_t)N * HID;

    mlp_kernel<<<dim3(N / ROWS, 2), 128, 0, stream>>>(
        emb, Wl1, bl1, Wl2, bl2, Wa1, ba1, Wa2, ba2, latL, latA, ws);

    // 1504 blocks x 256 threads = 6016 waves, exactly one 64-edge batch each
    edge_kernel<<<1504, 256, 0, stream>>>(
        latL, latA, aa, fd, ei, ne, pe, ewp, swp, out, ws);

    finalize_kernel<<<1, 64, 0, stream>>>(ws, out);
}